// Round 1
// baseline (461.744 us; speedup 1.0000x reference)
//
#include <hip/hip_runtime.h>

// VCDN cross-feature matvec: out[c] = relu(W[c,:] @ cfdt + b[c])
// cfdt[d] = p01[d/2304] * p23[d%2304]  (rank-1 structure, never materialized)
// Memory-bound: W = 339.7 MB read once. Floor ~54 us @ 6.3 TB/s.

#define N_CLASSES 16
#define VIEW_DIM  48
#define P         2304      // 48*48
#define D         5308416   // 2304*2304
#define CHUNKS    256       // blocks per class
#define BLOCK     256

__global__ void vcdn_zero_ws(float* ws) {
    if (threadIdx.x < N_CLASSES) ws[threadIdx.x] = 0.0f;
}

__global__ __launch_bounds__(BLOCK) void vcdn_main(
        const float* __restrict__ x,
        const float* __restrict__ W,
        float* __restrict__ ws) {
    __shared__ float p01[P];
    __shared__ float p23[P];

    const float* x0 = x;
    const float* x1 = x + VIEW_DIM;
    const float* x2 = x + 2 * VIEW_DIM;
    const float* x3 = x + 3 * VIEW_DIM;

    // Build the two 48x48 outer products in LDS (9 KB each).
    for (int t = threadIdx.x; t < P; t += BLOCK) {
        int i = t / VIEW_DIM;
        int j = t - i * VIEW_DIM;
        p01[t] = x0[i] * x1[j];
        p23[t] = x2[i] * x3[j];
    }
    __syncthreads();

    const int c     = blockIdx.x / CHUNKS;
    const int chunk = blockIdx.x - c * CHUNKS;

    const float4* W4 = (const float4*)(W + (size_t)c * D);
    const float4* q4 = (const float4*)p23;

    const int nvec   = D / 4;           // 1,327,104 float4s per class row
    const int stride = CHUNKS * BLOCK;  // 65,536 threads per class

    float acc = 0.0f;
    for (int v = chunk * BLOCK + threadIdx.x; v < nvec; v += stride) {
        int d    = v << 2;
        int a    = d / P;          // magic-mul div by 2304
        int bidx = d - a * P;      // 0..2300, multiple of 4
        float4 w = W4[v];          // coalesced 16 B/lane stream of W
        float4 q = q4[bidx >> 2];  // consecutive lanes -> consecutive LDS b128
        acc += p01[a] * (w.x * q.x + w.y * q.y + w.z * q.z + w.w * q.w);
    }

    // wave64 butterfly reduce
    for (int off = 32; off > 0; off >>= 1)
        acc += __shfl_down(acc, off, 64);

    __shared__ float wsum[BLOCK / 64];
    const int lane = threadIdx.x & 63;
    const int wid  = threadIdx.x >> 6;
    if (lane == 0) wsum[wid] = acc;
    __syncthreads();
    if (threadIdx.x == 0) {
        float s = wsum[0] + wsum[1] + wsum[2] + wsum[3];
        atomicAdd(&ws[c], s);  // 4096 atomics total over 16 addresses — negligible
    }
}

__global__ void vcdn_finalize(const float* __restrict__ ws,
                              const float* __restrict__ b,
                              float* __restrict__ out) {
    int c = threadIdx.x;
    if (c < N_CLASSES) {
        float v = ws[c] + b[c];
        out[c] = v > 0.0f ? v : 0.0f;
    }
}

extern "C" void kernel_launch(void* const* d_in, const int* in_sizes, int n_in,
                              void* d_out, int out_size, void* d_ws, size_t ws_size,
                              hipStream_t stream) {
    const float* x = (const float*)d_in[0];   // (4, 48) fp32
    const float* W = (const float*)d_in[1];   // (16, D) fp32
    const float* b = (const float*)d_in[2];   // (16,) fp32
    float* out = (float*)d_out;               // (16,) fp32
    float* ws  = (float*)d_ws;

    vcdn_zero_ws<<<1, 64, 0, stream>>>(ws);
    vcdn_main<<<N_CLASSES * CHUNKS, BLOCK, 0, stream>>>(x, W, ws);
    vcdn_finalize<<<1, 64, 0, stream>>>(ws, b, out);
}

// Round 2
// 449.415 us; speedup vs baseline: 1.0274x; 1.0274x over previous
//
#include <hip/hip_runtime.h>

// VCDN cross-feature matvec: out[c] = relu(W[c,:] @ cfdt + b[c])
// cfdt[(a*2304)+bb] = p01[a] * p23[bb]  (rank-1, never materialized)
// Memory floor: W = 339.7 MB fp32 read once ~ 51 us @ 6.6 TB/s.
// Round 2: 2 launches (no zero+atomic pass), div-free row-aligned K-loop,
// p23 fragments hoisted to registers (9 x float4), p01 folded to a per-row scalar.

#define N_CLASSES 16
#define VIEW_DIM  48
#define P         2304            // 48*48 (row length in floats)
#define ROW_F4    (P / 4)         // 576 float4 per row
#define CHUNKS    288             // blocks per class -> 8 rows per block
#define ROWS_PER_BLOCK 8
#define ROWS_PER_WAVE  2          // 4 waves per block
#define BLOCK     256
#define ITERS     (ROW_F4 / 64)   // 9 float4 per lane per row

__global__ __launch_bounds__(BLOCK) void vcdn_main(
        const float* __restrict__ x,
        const float* __restrict__ W,
        float* __restrict__ ws) {
    __shared__ float p23[P];

    const float* x0 = x;
    const float* x1 = x + VIEW_DIM;
    const float* x2 = x + 2 * VIEW_DIM;
    const float* x3 = x + 3 * VIEW_DIM;

    for (int t = threadIdx.x; t < P; t += BLOCK) {
        int i = t / VIEW_DIM;
        int j = t - i * VIEW_DIM;
        p23[t] = x2[i] * x3[j];
    }
    __syncthreads();

    const int c     = blockIdx.x / CHUNKS;
    const int chunk = blockIdx.x - c * CHUNKS;
    const int wid   = threadIdx.x >> 6;
    const int lane  = threadIdx.x & 63;

    // Hoist this lane's 9 loop-invariant p23 fragments into registers.
    const float4* q4 = (const float4*)p23;
    float4 q[ITERS];
#pragma unroll
    for (int it = 0; it < ITERS; ++it) q[it] = q4[it * 64 + lane];

    const int row0 = chunk * ROWS_PER_BLOCK + wid * ROWS_PER_WAVE;
    float acc = 0.0f;

#pragma unroll
    for (int r = 0; r < ROWS_PER_WAVE; ++r) {
        const int a = row0 + r;                 // row index in [0, 2304)
        const int i = a / VIEW_DIM;
        const int j = a - i * VIEW_DIM;
        const float s01 = x0[i] * x1[j];        // wave-uniform scalar

        const float4* Wrow =
            (const float4*)(W + (size_t)c * (size_t)P * P + (size_t)a * P);

        float racc = 0.0f;
#pragma unroll
        for (int it = 0; it < ITERS; ++it) {
            float4 w = Wrow[it * 64 + lane];    // coalesced 1 KB/wave stream
            racc += w.x * q[it].x + w.y * q[it].y + w.z * q[it].z + w.w * q[it].w;
        }
        acc += s01 * racc;
    }

    // wave64 reduce, then 4 waves -> 1 value, pure store (no zero, no atomic)
    for (int off = 32; off; off >>= 1)
        acc += __shfl_down(acc, off, 64);

    __shared__ float wsum[BLOCK / 64];
    if (lane == 0) wsum[wid] = acc;
    __syncthreads();
    if (threadIdx.x == 0)
        ws[c * CHUNKS + chunk] = wsum[0] + wsum[1] + wsum[2] + wsum[3];
}

__global__ void vcdn_finalize(const float* __restrict__ ws,
                              const float* __restrict__ b,
                              float* __restrict__ out) {
    __shared__ float s[BLOCK];
    const int t   = threadIdx.x;
    const int c   = t >> 4;        // 16 threads per class
    const int sub = t & 15;
    float sum = 0.0f;
    for (int k = sub; k < CHUNKS; k += 16)     // 288/16 = 18 partials each
        sum += ws[c * CHUNKS + k];
    s[t] = sum;
    __syncthreads();
    if (t < N_CLASSES) {
        float tot = 0.0f;
#pragma unroll
        for (int k = 0; k < 16; ++k) tot += s[t * 16 + k];
        tot += b[t];
        out[t] = tot > 0.0f ? tot : 0.0f;
    }
}

extern "C" void kernel_launch(void* const* d_in, const int* in_sizes, int n_in,
                              void* d_out, int out_size, void* d_ws, size_t ws_size,
                              hipStream_t stream) {
    const float* x = (const float*)d_in[0];   // (4, 48) fp32
    const float* W = (const float*)d_in[1];   // (16, D) fp32
    const float* b = (const float*)d_in[2];   // (16,) fp32
    float* out = (float*)d_out;               // (16,) fp32
    float* ws  = (float*)d_ws;                // partials: 16*288 floats

    vcdn_main<<<N_CLASSES * CHUNKS, BLOCK, 0, stream>>>(x, W, ws);
    vcdn_finalize<<<1, BLOCK, 0, stream>>>(ws, b, out);
}

// Round 3
// 421.921 us; speedup vs baseline: 1.0944x; 1.0652x over previous
//
#include <hip/hip_runtime.h>

// VCDN cross-feature matvec: out[c] = relu(W[c,:] @ cfdt + b[c])
// cfdt[(a*2304)+bb] = p01[a] * p23[bb]  (rank-1, never materialized)
// Memory floor: W = 339.7 MB fp32 read once ~ 52 us @ 6.6 TB/s achieved.
// Round 3: nontemporal W loads (read-once stream > LLC), 16 rows/block
// (grid 2304 = 9 blocks/CU), 4 rows/wave. Traffic identical to R2.

#define N_CLASSES 16
#define VIEW_DIM  48
#define P         2304            // 48*48 (row length in floats)
#define ROW_F4    (P / 4)         // 576 float4 per row
#define ROWS_PER_BLOCK 16
#define CHUNKS    (P / ROWS_PER_BLOCK)   // 144 blocks per class
#define ROWS_PER_WAVE  4          // 4 waves per block
#define BLOCK     256
#define ITERS     (ROW_F4 / 64)   // 9 float4 per lane per row

typedef float v4f __attribute__((ext_vector_type(4)));

__global__ __launch_bounds__(BLOCK) void vcdn_main(
        const float* __restrict__ x,
        const float* __restrict__ W,
        float* __restrict__ ws) {
    __shared__ float p23[P];

    const float* x0 = x;
    const float* x1 = x + VIEW_DIM;
    const float* x2 = x + 2 * VIEW_DIM;
    const float* x3 = x + 3 * VIEW_DIM;

    for (int t = threadIdx.x; t < P; t += BLOCK) {
        int i = t / VIEW_DIM;
        int j = t - i * VIEW_DIM;
        p23[t] = x2[i] * x3[j];
    }
    __syncthreads();

    const int c     = blockIdx.x / CHUNKS;
    const int chunk = blockIdx.x - c * CHUNKS;
    const int wid   = threadIdx.x >> 6;
    const int lane  = threadIdx.x & 63;

    // This lane's 9 loop-invariant p23 fragments -> registers.
    const v4f* q4 = (const v4f*)p23;
    v4f q[ITERS];
#pragma unroll
    for (int it = 0; it < ITERS; ++it) q[it] = q4[it * 64 + lane];

    const int row0 = chunk * ROWS_PER_BLOCK + wid * ROWS_PER_WAVE;
    float acc = 0.0f;

#pragma unroll
    for (int r = 0; r < ROWS_PER_WAVE; ++r) {
        const int a = row0 + r;                 // row index in [0, 2304)
        const int i = a / VIEW_DIM;
        const int j = a - i * VIEW_DIM;
        const float s01 = x0[i] * x1[j];        // wave-uniform scalar

        const v4f* Wrow =
            (const v4f*)(W + (size_t)c * (size_t)P * P + (size_t)a * P);

        float racc = 0.0f;
#pragma unroll
        for (int it = 0; it < ITERS; ++it) {
            v4f w = __builtin_nontemporal_load(Wrow + it * 64 + lane);
            racc += w.x * q[it].x + w.y * q[it].y + w.z * q[it].z + w.w * q[it].w;
        }
        acc += s01 * racc;
    }

    // wave64 reduce, then 4 waves -> 1 value, pure store
    for (int off = 32; off; off >>= 1)
        acc += __shfl_down(acc, off, 64);

    __shared__ float wsum[BLOCK / 64];
    if (lane == 0) wsum[wid] = acc;
    __syncthreads();
    if (threadIdx.x == 0)
        ws[c * CHUNKS + chunk] = wsum[0] + wsum[1] + wsum[2] + wsum[3];
}

__global__ void vcdn_finalize(const float* __restrict__ ws,
                              const float* __restrict__ b,
                              float* __restrict__ out) {
    __shared__ float s[BLOCK];
    const int t   = threadIdx.x;
    const int c   = t >> 4;        // 16 threads per class
    const int sub = t & 15;
    float sum = 0.0f;
    for (int k = sub; k < CHUNKS; k += 16)     // 144/16 = 9 partials each
        sum += ws[c * CHUNKS + k];
    s[t] = sum;
    __syncthreads();
    if (t < N_CLASSES) {
        float tot = 0.0f;
#pragma unroll
        for (int k = 0; k < 16; ++k) tot += s[t * 16 + k];
        tot += b[t];
        out[t] = tot > 0.0f ? tot : 0.0f;
    }
}

extern "C" void kernel_launch(void* const* d_in, const int* in_sizes, int n_in,
                              void* d_out, int out_size, void* d_ws, size_t ws_size,
                              hipStream_t stream) {
    const float* x = (const float*)d_in[0];   // (4, 48) fp32
    const float* W = (const float*)d_in[1];   // (16, D) fp32
    const float* b = (const float*)d_in[2];   // (16,) fp32
    float* out = (float*)d_out;               // (16,) fp32
    float* ws  = (float*)d_ws;                // partials: 16*144 floats

    vcdn_main<<<N_CLASSES * CHUNKS, BLOCK, 0, stream>>>(x, W, ws);
    vcdn_finalize<<<1, BLOCK, 0, stream>>>(ws, b, out);
}

// Round 4
// 415.561 us; speedup vs baseline: 1.1111x; 1.0153x over previous
//
#include <hip/hip_runtime.h>

// VCDN cross-feature matvec: out[c] = relu(W[c,:] @ cfdt + b[c])
// cfdt[(a*2304)+bb] = p01[a] * p23[bb]  (rank-1, never materialized)
// Memory floor: W = 339.7 MB fp32 read once ~ 52 us @ 6.6 TB/s achieved.
// Round 4: perfect-residency grid — 1536 blocks (24 rows/block), 6 blocks/CU
// x 4 waves = 24 waves/CU, ALL blocks co-resident, zero dispatch tail.
// nt W loads kept (read-once stream, skip LLC allocate). Traffic identical.

#define N_CLASSES 16
#define VIEW_DIM  48
#define P         2304            // 48*48 (row length in floats)
#define ROW_F4    (P / 4)         // 576 float4 per row
#define ROWS_PER_BLOCK 24
#define CHUNKS    (P / ROWS_PER_BLOCK)   // 96 blocks per class -> grid 1536
#define ROWS_PER_WAVE  6          // 4 waves per block
#define BLOCK     256
#define ITERS     (ROW_F4 / 64)   // 9 float4 per lane per row

typedef float v4f __attribute__((ext_vector_type(4)));

__global__ __launch_bounds__(BLOCK, 6) void vcdn_main(
        const float* __restrict__ x,
        const float* __restrict__ W,
        float* __restrict__ ws) {
    __shared__ float p23[P];

    const float* x0 = x;
    const float* x1 = x + VIEW_DIM;
    const float* x2 = x + 2 * VIEW_DIM;
    const float* x3 = x + 3 * VIEW_DIM;

    for (int t = threadIdx.x; t < P; t += BLOCK) {
        int i = t / VIEW_DIM;
        int j = t - i * VIEW_DIM;
        p23[t] = x2[i] * x3[j];
    }
    __syncthreads();

    const int c     = blockIdx.x / CHUNKS;
    const int chunk = blockIdx.x - c * CHUNKS;
    const int wid   = threadIdx.x >> 6;
    const int lane  = threadIdx.x & 63;

    // This lane's 9 loop-invariant p23 fragments -> registers (36 VGPRs).
    const v4f* q4 = (const v4f*)p23;
    v4f q[ITERS];
#pragma unroll
    for (int it = 0; it < ITERS; ++it) q[it] = q4[it * 64 + lane];

    const int row0 = chunk * ROWS_PER_BLOCK + wid * ROWS_PER_WAVE;
    float acc0 = 0.0f, acc1 = 0.0f;   // two chains, alternate rows

#pragma unroll
    for (int r = 0; r < ROWS_PER_WAVE; ++r) {
        const int a = row0 + r;                 // row index in [0, 2304)
        const int i = a / VIEW_DIM;
        const int j = a - i * VIEW_DIM;
        const float s01 = x0[i] * x1[j];        // wave-uniform scalar

        const v4f* Wrow =
            (const v4f*)(W + (size_t)c * (size_t)P * P + (size_t)a * P);

        float racc = 0.0f;
#pragma unroll
        for (int it = 0; it < ITERS; ++it) {
            v4f w = __builtin_nontemporal_load(Wrow + it * 64 + lane);
            racc += w.x * q[it].x + w.y * q[it].y + w.z * q[it].z + w.w * q[it].w;
        }
        if (r & 1) acc1 += s01 * racc;
        else       acc0 += s01 * racc;
    }
    float acc = acc0 + acc1;

    // wave64 reduce, then 4 waves -> 1 value, pure store
    for (int off = 32; off; off >>= 1)
        acc += __shfl_down(acc, off, 64);

    __shared__ float wsum[BLOCK / 64];
    if (lane == 0) wsum[wid] = acc;
    __syncthreads();
    if (threadIdx.x == 0)
        ws[c * CHUNKS + chunk] = wsum[0] + wsum[1] + wsum[2] + wsum[3];
}

__global__ void vcdn_finalize(const float* __restrict__ ws,
                              const float* __restrict__ b,
                              float* __restrict__ out) {
    __shared__ float s[BLOCK];
    const int t   = threadIdx.x;
    const int c   = t >> 4;        // 16 threads per class
    const int sub = t & 15;
    float sum = 0.0f;
    for (int k = sub; k < CHUNKS; k += 16)     // 96/16 = 6 partials each
        sum += ws[c * CHUNKS + k];
    s[t] = sum;
    __syncthreads();
    if (t < N_CLASSES) {
        float tot = 0.0f;
#pragma unroll
        for (int k = 0; k < 16; ++k) tot += s[t * 16 + k];
        tot += b[t];
        out[t] = tot > 0.0f ? tot : 0.0f;
    }
}

extern "C" void kernel_launch(void* const* d_in, const int* in_sizes, int n_in,
                              void* d_out, int out_size, void* d_ws, size_t ws_size,
                              hipStream_t stream) {
    const float* x = (const float*)d_in[0];   // (4, 48) fp32
    const float* W = (const float*)d_in[1];   // (16, D) fp32
    const float* b = (const float*)d_in[2];   // (16,) fp32
    float* out = (float*)d_out;               // (16,) fp32
    float* ws  = (float*)d_ws;                // partials: 16*96 floats

    vcdn_main<<<N_CLASSES * CHUNKS, BLOCK, 0, stream>>>(x, W, ws);
    vcdn_finalize<<<1, BLOCK, 0, stream>>>(ws, b, out);
}